// Round 1
// baseline (2387.089 us; speedup 1.0000x reference)
//
#include <hip/hip_runtime.h>
#include <hip/hip_bf16.h>

// ---------------------------------------------------------------------------
// Problem constants (B=2, S=2048, D=1024; N_QK=N_V=4096, N_KNOW=8192)
// M = B*S = 4096 token rows.
// Outputs (flat, fp32): g_Q[4096*4096], g_K[...], g_V[...], aux_attn[1],
//                       g_know[4096*8192], aux_know[1]
// ---------------------------------------------------------------------------

#define M_ROWS 4096
#define DIM    1024
#define N_QK   4096
#define N_KNOW 8192

// ---------------------------------------------------------------------------
// tau kernel: tau4[row*4 + {0,1,2,3}] = x_row @ {w_attn[:,0..2], w_know} + bias
// ---------------------------------------------------------------------------
__global__ __launch_bounds__(256) void tau_kernel(
    const float* __restrict__ x, const float* __restrict__ w_attn,
    const float* __restrict__ b_attn, const float* __restrict__ w_know,
    const float* __restrict__ b_know, float* __restrict__ tau4, int D)
{
    __shared__ float s_f[4][4]; // [wave][j]
    const int row = blockIdx.x;
    const int tid = threadIdx.x;
    const float* xr = x + (size_t)row * D;
    float p0 = 0.f, p1 = 0.f, p2 = 0.f, p3 = 0.f;
    for (int d = tid; d < D; d += 256) {
        float xv = xr[d];
        p0 += xv * w_attn[d * 3 + 0];
        p1 += xv * w_attn[d * 3 + 1];
        p2 += xv * w_attn[d * 3 + 2];
        p3 += xv * w_know[d];
    }
#pragma unroll
    for (int o = 32; o > 0; o >>= 1) {
        p0 += __shfl_down(p0, o, 64);
        p1 += __shfl_down(p1, o, 64);
        p2 += __shfl_down(p2, o, 64);
        p3 += __shfl_down(p3, o, 64);
    }
    const int lane = tid & 63, wv = tid >> 6;
    if (lane == 0) { s_f[wv][0] = p0; s_f[wv][1] = p1; s_f[wv][2] = p2; s_f[wv][3] = p3; }
    __syncthreads();
    if (tid < 4) {
        float v = s_f[0][tid] + s_f[1][tid] + s_f[2][tid] + s_f[3][tid];
        v += (tid < 3) ? b_attn[tid] : b_know[0];
        tau4[(size_t)row * 4 + tid] = v;
    }
}

// ---------------------------------------------------------------------------
// SGEMM NT: C[M x N] = A[M x K] * B[N x K]^T   (both K-contiguous, fp32)
// 128x128 tile, BK=16, 256 threads, 8x8 microtile per thread.
// M, N multiples of 128; K multiple of 16.
// ---------------------------------------------------------------------------
__global__ __launch_bounds__(256) void sgemm_nt(
    const float* __restrict__ A, const float* __restrict__ B,
    float* __restrict__ C, int M, int N, int K)
{
    __shared__ float As[16][128];
    __shared__ float Bs[16][128];
    const int tid = threadIdx.x;
    const int m0 = blockIdx.y * 128;
    const int n0 = blockIdx.x * 128;
    const int tx = tid & 15;  // n direction
    const int ty = tid >> 4;  // m direction
    float acc[8][8];
#pragma unroll
    for (int i = 0; i < 8; ++i)
#pragma unroll
        for (int j = 0; j < 8; ++j) acc[i][j] = 0.f;

    const float* Ab = A + (size_t)m0 * K;
    const float* Bb = B + (size_t)n0 * K;

    for (int k0 = 0; k0 < K; k0 += 16) {
#pragma unroll
        for (int i = 0; i < 2; ++i) {
            int l = tid + i * 256;       // 0..511
            int row = l >> 2;            // 0..127
            int ks = (l & 3) << 2;       // 0,4,8,12
            const float4 av = *(const float4*)(Ab + (size_t)row * K + k0 + ks);
            As[ks + 0][row] = av.x; As[ks + 1][row] = av.y;
            As[ks + 2][row] = av.z; As[ks + 3][row] = av.w;
            const float4 bv = *(const float4*)(Bb + (size_t)row * K + k0 + ks);
            Bs[ks + 0][row] = bv.x; Bs[ks + 1][row] = bv.y;
            Bs[ks + 2][row] = bv.z; Bs[ks + 3][row] = bv.w;
        }
        __syncthreads();
#pragma unroll
        for (int k = 0; k < 16; ++k) {
            float a[8], b[8];
            *(float4*)&a[0] = *(const float4*)&As[k][ty * 8];
            *(float4*)&a[4] = *(const float4*)&As[k][ty * 8 + 4];
            *(float4*)&b[0] = *(const float4*)&Bs[k][tx * 8];
            *(float4*)&b[4] = *(const float4*)&Bs[k][tx * 8 + 4];
#pragma unroll
            for (int i = 0; i < 8; ++i)
#pragma unroll
                for (int j = 0; j < 8; ++j) acc[i][j] += a[i] * b[j];
        }
        __syncthreads();
    }
#pragma unroll
    for (int i = 0; i < 8; ++i) {
        float* crow = C + (size_t)(m0 + ty * 8 + i) * N + n0 + tx * 8;
        *(float4*)crow = *(float4*)&acc[i][0];
        *(float4*)(crow + 4) = *(float4*)&acc[i][4];
    }
}

// ---------------------------------------------------------------------------
// Gate kernel: one block per row. Exact k-th-largest selection on
// raw = score - tau via bitwise binary search on order-preserving uint keys.
// Monotone raw -> exp_gate means ranking by raw == ranking by exp_gate
// (the 1e-8 blip at raw==0 is irrelevant for the top-k region).
// ---------------------------------------------------------------------------
__device__ __forceinline__ unsigned floatToKey(float f) {
    unsigned b = __float_as_uint(f);
    return (b & 0x80000000u) ? ~b : (b | 0x80000000u);
}
__device__ __forceinline__ float keyToFloat(unsigned key) {
    unsigned b = (key & 0x80000000u) ? (key & 0x7FFFFFFFu) : ~key;
    return __uint_as_float(b);
}
__device__ __forceinline__ float gateOf(float raw) {
    return raw > 0.f ? raw : 1e-8f * expf(raw);
}

__global__ __launch_bounds__(256) void gate_kernel(
    const float* __restrict__ scores, const float* __restrict__ tau4,
    int tauIdx, int N, int ksel,
    float* __restrict__ outg, float* __restrict__ colsum)
{
    extern __shared__ unsigned keys[];  // N uints
    __shared__ int s_i[4];
    __shared__ unsigned s_u[4];
    __shared__ float s_f[4];

    const int tid = threadIdx.x;
    const int lane = tid & 63, wv = tid >> 6;
    const int row = blockIdx.x;
    const float t = tau4[(size_t)row * 4 + tauIdx];
    const float* srow = scores + (size_t)row * N;

    // load, keyify, track max
    unsigned kmaxl = 0u;
    for (int n = tid; n < N; n += 256) {
        float raw = srow[n] - t;
        unsigned key = floatToKey(raw);
        keys[n] = key;
        kmaxl = kmaxl > key ? kmaxl : key;
    }
#pragma unroll
    for (int o = 32; o > 0; o >>= 1) {
        unsigned other = __shfl_down(kmaxl, o, 64);
        kmaxl = kmaxl > other ? kmaxl : other;
    }
    if (lane == 0) s_u[wv] = kmaxl;
    __syncthreads();  // also publishes keys[]
    unsigned kmax = s_u[0];
    kmax = kmax > s_u[1] ? kmax : s_u[1];
    kmax = kmax > s_u[2] ? kmax : s_u[2];
    kmax = kmax > s_u[3] ? kmax : s_u[3];
    __syncthreads();

    // binary search for exact k-th largest key
    unsigned lo = 0u, hi = kmax;
    while (lo < hi) {
        unsigned mid = lo + ((hi - lo + 1u) >> 1);
        int c = 0;
        for (int n = tid; n < N; n += 256) c += (keys[n] >= mid) ? 1 : 0;
#pragma unroll
        for (int o = 32; o > 0; o >>= 1) c += __shfl_down(c, o, 64);
        if (lane == 0) s_i[wv] = c;
        __syncthreads();
        int total = s_i[0] + s_i[1] + s_i[2] + s_i[3];
        __syncthreads();
        if (total >= ksel) lo = mid; else hi = mid - 1u;
    }
    const unsigned vk = lo;

    // sum of kept exp_gate
    float lsum = 0.f;
    for (int n = tid; n < N; n += 256) {
        unsigned key = keys[n];
        if (key >= vk) {
            float raw = keyToFloat(key);
            lsum += expf(gateOf(raw)) - 1.f;
        }
    }
#pragma unroll
    for (int o = 32; o > 0; o >>= 1) lsum += __shfl_down(lsum, o, 64);
    if (lane == 0) s_f[wv] = lsum;
    __syncthreads();
    const float gate_sum = s_f[0] + s_f[1] + s_f[2] + s_f[3] + 1e-8f;

    const float rawmax = keyToFloat(kmax);
    const float egmax = expf(gateOf(rawmax)) - 1.f;
    const float strength = tanhf(egmax);
    const float scale = strength / gate_sum;

    // write output row + column-sum atomics
    float* orow = outg + (size_t)row * N;
    for (int n = tid; n < N; n += 256) {
        float g = 0.f;
        unsigned key = keys[n];
        if (key >= vk) {
            float raw = keyToFloat(key);
            g = (expf(gateOf(raw)) - 1.f) * scale;
            atomicAdd(&colsum[n], g);
        }
        orow[n] = g;
    }
}

// ---------------------------------------------------------------------------
// Aux kernel: aux_attn = sum over {gQ,gK,gV} cols of (mean - 1/4096)^2 * 4096
//             aux_know = sum over know cols of (mean - 1/8192)^2 * 8192
// colsum layout: gQ[4096] gK[4096] gV[4096] gknow[8192]
// ---------------------------------------------------------------------------
__global__ __launch_bounds__(256) void aux_kernel(
    const float* __restrict__ colsum,
    float* __restrict__ auxAttn, float* __restrict__ auxKnow)
{
    __shared__ float s_a[4];
    __shared__ float s_b[4];
    const int tid = threadIdx.x;
    const int lane = tid & 63, wv = tid >> 6;
    const float invM = 1.f / 4096.f;

    float sa = 0.f;
    const float tqk = 1.f / 4096.f;
    for (int i = tid; i < 3 * N_QK; i += 256) {
        float m = colsum[i] * invM - tqk;
        sa += m * m;
    }
    float sk = 0.f;
    const float tkn = 1.f / 8192.f;
    for (int i = tid; i < N_KNOW; i += 256) {
        float m = colsum[3 * N_QK + i] * invM - tkn;
        sk += m * m;
    }
#pragma unroll
    for (int o = 32; o > 0; o >>= 1) {
        sa += __shfl_down(sa, o, 64);
        sk += __shfl_down(sk, o, 64);
    }
    if (lane == 0) { s_a[wv] = sa; s_b[wv] = sk; }
    __syncthreads();
    if (tid == 0) {
        auxAttn[0] = (s_a[0] + s_a[1] + s_a[2] + s_a[3]) * 4096.f;
        auxKnow[0] = (s_b[0] + s_b[1] + s_b[2] + s_b[3]) * 8192.f;
    }
}

// ---------------------------------------------------------------------------
// Launch
// ---------------------------------------------------------------------------
extern "C" void kernel_launch(void* const* d_in, const int* in_sizes, int n_in,
                              void* d_out, int out_size, void* d_ws, size_t ws_size,
                              hipStream_t stream)
{
    const float* x        = (const float*)d_in[0];
    const float* qk_emb   = (const float*)d_in[1];
    const float* v_emb    = (const float*)d_in[2];
    const float* know_emb = (const float*)d_in[3];
    const float* w_attn   = (const float*)d_in[4];
    const float* b_attn   = (const float*)d_in[5];
    const float* w_know   = (const float*)d_in[6];
    const float* b_know   = (const float*)d_in[7];
    float* out = (float*)d_out;

    const int M = M_ROWS, D = DIM;

    float* gQ   = out;
    float* gK   = gQ + (size_t)M * N_QK;
    float* gV   = gK + (size_t)M * N_QK;
    float* auxA = gV + (size_t)M * N_QK;
    float* gKn  = auxA + 1;
    float* auxK = gKn + (size_t)M * N_KNOW;

    // ws tail: tau4 (M*4 floats) + colsums (3*4096 + 8192 floats)
    const size_t nColsum = 3 * (size_t)N_QK + N_KNOW;
    const size_t tailBytes = ((size_t)M * 4 + nColsum) * sizeof(float);
    size_t tailStart = (ws_size - tailBytes) & ~(size_t)255;
    float* tau4 = (float*)((char*)d_ws + tailStart);
    float* colsums = tau4 + (size_t)M * 4;
    float* scores = (float*)d_ws;  // [0, tailStart) bytes available

    hipMemsetAsync(colsums, 0, nColsum * sizeof(float), stream);
    tau_kernel<<<M, 256, 0, stream>>>(x, w_attn, b_attn, w_know, b_know, tau4, D);

    auto rowsChunk = [&](int N) -> int {
        size_t rc = tailStart / ((size_t)N * sizeof(float));
        if (rc > (size_t)M) rc = (size_t)M;
        rc = (rc / 128) * 128;
        if (rc < 128) rc = 128;  // assume ws is at least ~2 MB
        return (int)rc;
    };

    // ---- scores_qk -> g_Q, g_K ----
    {
        int rc = rowsChunk(N_QK);
        for (int r0 = 0; r0 < M; r0 += rc) {
            int rows = (M - r0 < rc) ? (M - r0) : rc;
            sgemm_nt<<<dim3(N_QK / 128, rows / 128), 256, 0, stream>>>(
                x + (size_t)r0 * D, qk_emb, scores, rows, N_QK, D);
            gate_kernel<<<rows, 256, N_QK * sizeof(unsigned), stream>>>(
                scores, tau4 + (size_t)r0 * 4, 0, N_QK, 64,
                gQ + (size_t)r0 * N_QK, colsums);
            gate_kernel<<<rows, 256, N_QK * sizeof(unsigned), stream>>>(
                scores, tau4 + (size_t)r0 * 4, 1, N_QK, 64,
                gK + (size_t)r0 * N_QK, colsums + N_QK);
        }
    }
    // ---- scores_v -> g_V ----
    {
        int rc = rowsChunk(N_QK);
        for (int r0 = 0; r0 < M; r0 += rc) {
            int rows = (M - r0 < rc) ? (M - r0) : rc;
            sgemm_nt<<<dim3(N_QK / 128, rows / 128), 256, 0, stream>>>(
                x + (size_t)r0 * D, v_emb, scores, rows, N_QK, D);
            gate_kernel<<<rows, 256, N_QK * sizeof(unsigned), stream>>>(
                scores, tau4 + (size_t)r0 * 4, 2, N_QK, 64,
                gV + (size_t)r0 * N_QK, colsums + 2 * N_QK);
        }
    }
    // ---- scores_know -> g_know ----
    {
        int rc = rowsChunk(N_KNOW);
        for (int r0 = 0; r0 < M; r0 += rc) {
            int rows = (M - r0 < rc) ? (M - r0) : rc;
            sgemm_nt<<<dim3(N_KNOW / 128, rows / 128), 256, 0, stream>>>(
                x + (size_t)r0 * D, know_emb, scores, rows, N_KNOW, D);
            gate_kernel<<<rows, 256, N_KNOW * sizeof(unsigned), stream>>>(
                scores, tau4 + (size_t)r0 * 4, 3, N_KNOW, 128,
                gKn + (size_t)r0 * N_KNOW, colsums + 3 * N_QK);
        }
    }

    aux_kernel<<<1, 256, 0, stream>>>(colsums, auxA, auxK);
}

// Round 4
// 1353.168 us; speedup vs baseline: 1.7641x; 1.7641x over previous
//
#include <hip/hip_runtime.h>
#include <hip/hip_bf16.h>

// ---------------------------------------------------------------------------
// B=2,S=2048,D=1024; M=4096 rows. N_QK=N_V=4096, N_KNOW=8192.
// bf16x4 split GEMM (K-extended to 4096) on MFMA -> fp32-class scores written
// directly into d_out regions; gate kernels run IN-PLACE on those regions.
//   A' = [x_hi | x_hi | x_lo | x_lo]   (per 1024-dim row)
//   B' = [e_hi | e_lo | e_hi | e_lo]
//   A'.B' = (x_hi+x_lo)(e_hi+e_lo) = x.e exactly up to bf16 split residuals.
// ws holds only A_ext/B_ext bf16 staging (adaptively chunked) + tiny tail.
// ---------------------------------------------------------------------------

#define M_ROWS 4096
#define DIM    1024
#define KX     4096   // 4*DIM
#define N_QK   4096
#define N_KNOW 8192

typedef unsigned short ushortT;
typedef __attribute__((ext_vector_type(8))) short short8;   // 8 bf16 (4 VGPR)
typedef __attribute__((ext_vector_type(4))) float f32x4;

// ---------------------------------------------------------------------------
// tau kernel
// ---------------------------------------------------------------------------
__global__ __launch_bounds__(256) void tau_kernel(
    const float* __restrict__ x, const float* __restrict__ w_attn,
    const float* __restrict__ b_attn, const float* __restrict__ w_know,
    const float* __restrict__ b_know, float* __restrict__ tau4, int D)
{
    __shared__ float s_f[4][4];
    const int row = blockIdx.x;
    const int tid = threadIdx.x;
    const float* xr = x + (size_t)row * D;
    float p0 = 0.f, p1 = 0.f, p2 = 0.f, p3 = 0.f;
    for (int d = tid; d < D; d += 256) {
        float xv = xr[d];
        p0 += xv * w_attn[d * 3 + 0];
        p1 += xv * w_attn[d * 3 + 1];
        p2 += xv * w_attn[d * 3 + 2];
        p3 += xv * w_know[d];
    }
#pragma unroll
    for (int o = 32; o > 0; o >>= 1) {
        p0 += __shfl_down(p0, o, 64);
        p1 += __shfl_down(p1, o, 64);
        p2 += __shfl_down(p2, o, 64);
        p3 += __shfl_down(p3, o, 64);
    }
    const int lane = tid & 63, wv = tid >> 6;
    if (lane == 0) { s_f[wv][0] = p0; s_f[wv][1] = p1; s_f[wv][2] = p2; s_f[wv][3] = p3; }
    __syncthreads();
    if (tid < 4) {
        float v = s_f[0][tid] + s_f[1][tid] + s_f[2][tid] + s_f[3][tid];
        v += (tid < 3) ? b_attn[tid] : b_know[0];
        tau4[(size_t)row * 4 + tid] = v;
    }
}

// ---------------------------------------------------------------------------
// convert: rows x 1024 fp32 -> rows x 4096 bf16.
//   MODE_A: [H | H | L | L]     MODE_B: [H | L | H | L]
// ---------------------------------------------------------------------------
template <bool IS_A>
__global__ __launch_bounds__(256) void convert_ext(
    const float* __restrict__ src, ushortT* __restrict__ dst, int nElem4)
{
    int g = blockIdx.x * 256 + threadIdx.x;
    if (g >= nElem4) return;
    int row = g >> 8;            // 256 float4 groups per row
    int k4  = (g & 255) << 2;    // 0..1020
    const float4 v = *(const float4*)(src + (size_t)row * DIM + k4);
    float vv[4] = {v.x, v.y, v.z, v.w};
    ushortT hi[4], lo[4];
#pragma unroll
    for (int i = 0; i < 4; i++) {
        __hip_bfloat16 hb = __float2bfloat16(vv[i]);
        float r = vv[i] - __bfloat162float(hb);
        __hip_bfloat16 lb = __float2bfloat16(r);
        hi[i] = *(ushortT*)&hb; lo[i] = *(ushortT*)&lb;
    }
    ushort4 H = make_ushort4(hi[0], hi[1], hi[2], hi[3]);
    ushort4 L = make_ushort4(lo[0], lo[1], lo[2], lo[3]);
    ushortT* drow = dst + (size_t)row * KX;
    if (IS_A) {
        *(ushort4*)(drow + k4)            = H;
        *(ushort4*)(drow + DIM + k4)      = H;
        *(ushort4*)(drow + 2 * DIM + k4)  = L;
        *(ushort4*)(drow + 3 * DIM + k4)  = L;
    } else {
        *(ushort4*)(drow + k4)            = H;
        *(ushort4*)(drow + DIM + k4)      = L;
        *(ushort4*)(drow + 2 * DIM + k4)  = H;
        *(ushort4*)(drow + 3 * DIM + k4)  = L;
    }
}

// ---------------------------------------------------------------------------
// bf16 NT GEMM, m97 structure (verified pattern): 128x128 tile, BK=64,
// 256 thr = 2x2 waves, 64x64/wave, 4x4 of 16x16x32 MFMA.
// Plain row-major LDS [128][64]; global_load_lds width=16, linear flat map.
// ---------------------------------------------------------------------------
__global__ __launch_bounds__(256) void gemm_bt_bf16x4(
    const ushortT* __restrict__ A, const ushortT* __restrict__ B,
    float* __restrict__ C, long long ldc)
{
    __shared__ ushortT As[128 * 64];
    __shared__ ushortT Bs[128 * 64];
    const int tid = threadIdx.x;
    const int wave = tid >> 6, lane = tid & 63;
    const int quad = lane >> 4, l16 = lane & 15;
    const int wm = (wave >> 1) * 64, wn = (wave & 1) * 64;
    const long long m0 = (long long)blockIdx.y * 128;
    const long long n0 = (long long)blockIdx.x * 128;

    f32x4 acc[4][4] = {};

    const ushortT* gA[4];
    const ushortT* gB[4];
    ushortT* lA[4];
    ushortT* lB[4];
#pragma unroll
    for (int it = 0; it < 4; ++it) {
        int f = it * 256 + tid;          // 0..1023 flat 16B slot
        int r = f >> 3, sp = f & 7;      // row 0..127, seg 0..7
        gA[it] = A + (m0 + r) * KX + sp * 8;
        gB[it] = B + (n0 + r) * KX + sp * 8;
        lA[it] = As + f * 8;             // 16 B per slot
        lB[it] = Bs + f * 8;
    }
    const ushortT* pAr[4];
    const ushortT* pBr[4];
#pragma unroll
    for (int t = 0; t < 4; ++t) {
        pAr[t] = As + (wm + t * 16 + l16) * 64;
        pBr[t] = Bs + (wn + t * 16 + l16) * 64;
    }

    for (int k0 = 0; k0 < KX; k0 += 64) {
#pragma unroll
        for (int it = 0; it < 4; ++it) {
            __builtin_amdgcn_global_load_lds(
                (const __attribute__((address_space(1))) unsigned*)(const void*)(gA[it] + k0),
                (__attribute__((address_space(3))) unsigned*)(void*)lA[it], 16, 0, 0);
            __builtin_amdgcn_global_load_lds(
                (const __attribute__((address_space(1))) unsigned*)(const void*)(gB[it] + k0),
                (__attribute__((address_space(3))) unsigned*)(void*)lB[it], 16, 0, 0);
        }
        __syncthreads();
#pragma unroll
        for (int ks = 0; ks < 2; ++ks) {
            const int so = (ks * 4 + quad) * 8;
            short8 af[4], bfr[4];
#pragma unroll
            for (int t = 0; t < 4; ++t) {
                af[t]  = *(const short8*)(pAr[t] + so);
                bfr[t] = *(const short8*)(pBr[t] + so);
            }
#pragma unroll
            for (int i = 0; i < 4; ++i)
#pragma unroll
                for (int j = 0; j < 4; ++j)
                    acc[i][j] = __builtin_amdgcn_mfma_f32_16x16x32_bf16(af[i], bfr[j], acc[i][j], 0, 0, 0);
        }
        __syncthreads();
    }
    // C/D layout: col=lane&15, row=quad*4+reg  [m89/m91 verified]
#pragma unroll
    for (int i = 0; i < 4; ++i)
#pragma unroll
        for (int j = 0; j < 4; ++j) {
            long long col = n0 + wn + j * 16 + l16;
            long long rbase = m0 + wm + i * 16 + quad * 4;
#pragma unroll
            for (int r = 0; r < 4; ++r)
                C[(rbase + r) * ldc + col] = acc[i][j][r];
        }
}

// ---------------------------------------------------------------------------
// Gate kernel: one block/row, keys in registers, exact tie-correct top-k via
// bitwise binary search (early exit when count==k). Runs IN-PLACE on the
// score row (each thread only writes the indices it itself read).
// ---------------------------------------------------------------------------
__device__ __forceinline__ unsigned floatToKey(float f) {
    unsigned b = __float_as_uint(f);
    return (b & 0x80000000u) ? ~b : (b | 0x80000000u);
}
__device__ __forceinline__ float keyToFloat(unsigned key) {
    unsigned b = (key & 0x80000000u) ? (key & 0x7FFFFFFFu) : ~key;
    return __uint_as_float(b);
}
__device__ __forceinline__ float egate(float raw) {
    float g = raw > 0.f ? raw : 1e-8f * __expf(raw);
    return expf(g) - 1.f;
}

template <int NV, bool VEC4>
__global__ __launch_bounds__(256) void gate_kernel2(
    const float* __restrict__ scores, int N,
    const float* __restrict__ tau4, int tauA, int tauB,
    int ksel, float* __restrict__ outA, float* __restrict__ outB,
    float* __restrict__ colA, float* __restrict__ colB)
{
    __shared__ int s_i[4];
    __shared__ unsigned s_u[4];
    __shared__ float s_f[8];
    const int tid = threadIdx.x, lane = tid & 63, wv = tid >> 6;
    const int row = blockIdx.x;
    const bool hasB = (outB != nullptr);
    const float* srow = scores + (size_t)row * N;

    unsigned keys[NV * 4];
    unsigned kmax = 0u;
#pragma unroll
    for (int i = 0; i < NV; i++) {
        float v0, v1, v2, v3;
        const size_t nb = (size_t)(i * 256 + tid) * 4;
        if (VEC4) {
            float4 v = *(const float4*)(srow + nb);
            v0 = v.x; v1 = v.y; v2 = v.z; v3 = v.w;
        } else {
            v0 = srow[nb + 0]; v1 = srow[nb + 1];
            v2 = srow[nb + 2]; v3 = srow[nb + 3];
        }
        unsigned a = floatToKey(v0), b = floatToKey(v1);
        unsigned c = floatToKey(v2), d = floatToKey(v3);
        keys[i * 4 + 0] = a; keys[i * 4 + 1] = b;
        keys[i * 4 + 2] = c; keys[i * 4 + 3] = d;
        unsigned m1 = a > b ? a : b, m2 = c > d ? c : d;
        m1 = m1 > m2 ? m1 : m2;
        kmax = kmax > m1 ? kmax : m1;
    }
#pragma unroll
    for (int o = 32; o > 0; o >>= 1) {
        unsigned x = __shfl_down(kmax, o, 64);
        kmax = kmax > x ? kmax : x;
    }
    if (lane == 0) s_u[wv] = kmax;
    __syncthreads();
    { unsigned a = s_u[0], b = s_u[1], c = s_u[2], d = s_u[3];
      unsigned m1 = a > b ? a : b, m2 = c > d ? c : d; kmax = m1 > m2 ? m1 : m2; }
    __syncthreads();

    unsigned lo = 0u, hi = kmax, vk;
    for (;;) {
        if (lo >= hi) { vk = lo; break; }
        unsigned mid = lo + ((hi - lo + 1u) >> 1);
        int c = 0;
#pragma unroll
        for (int i = 0; i < NV * 4; i++) c += (keys[i] >= mid) ? 1 : 0;
#pragma unroll
        for (int o = 32; o > 0; o >>= 1) c += __shfl_down(c, o, 64);
        if (lane == 0) s_i[wv] = c;
        __syncthreads();
        int total = s_i[0] + s_i[1] + s_i[2] + s_i[3];
        __syncthreads();
        if (total == ksel) { vk = mid; break; }   // exact top-k set isolated
        if (total > ksel) lo = mid; else hi = mid - 1u;
    }

    const float tA = tau4[(size_t)row * 4 + tauA];
    const float tB = hasB ? tau4[(size_t)row * 4 + tauB] : 0.f;
    float sA = 0.f, sB = 0.f;
#pragma unroll
    for (int i = 0; i < NV * 4; i++) {
        if (keys[i] >= vk) {
            float s = keyToFloat(keys[i]);
            sA += egate(s - tA);
            if (hasB) sB += egate(s - tB);
        }
    }
#pragma unroll
    for (int o = 32; o > 0; o >>= 1) {
        sA += __shfl_down(sA, o, 64);
        sB += __shfl_down(sB, o, 64);
    }
    if (lane == 0) { s_f[wv] = sA; s_f[4 + wv] = sB; }
    __syncthreads();
    sA = s_f[0] + s_f[1] + s_f[2] + s_f[3];
    sB = s_f[4] + s_f[5] + s_f[6] + s_f[7];

    const float smax = keyToFloat(kmax);
    const float scaleA = tanhf(egate(smax - tA)) / (sA + 1e-8f);
    const float scaleB = hasB ? tanhf(egate(smax - tB)) / (sB + 1e-8f) : 0.f;

    float* orowA = outA + (size_t)row * N;
    float* orowB = hasB ? outB + (size_t)row * N : nullptr;
#pragma unroll
    for (int i = 0; i < NV; i++) {
        const size_t nb = (size_t)(i * 256 + tid) * 4;
        float ga[4], gb[4];
#pragma unroll
        for (int j = 0; j < 4; j++) {
            unsigned key = keys[i * 4 + j];
            float vA = 0.f, vB = 0.f;
            if (key >= vk) {
                float s = keyToFloat(key);
                vA = egate(s - tA) * scaleA;
                atomicAdd(&colA[nb + j], vA);
                if (hasB) { vB = egate(s - tB) * scaleB; atomicAdd(&colB[nb + j], vB); }
            }
            ga[j] = vA; gb[j] = vB;
        }
        if (VEC4) {
            *(float4*)(orowA + nb) = make_float4(ga[0], ga[1], ga[2], ga[3]);
            if (hasB) *(float4*)(orowB + nb) = make_float4(gb[0], gb[1], gb[2], gb[3]);
        } else {
#pragma unroll
            for (int j = 0; j < 4; j++) {
                orowA[nb + j] = ga[j];
                if (hasB) orowB[nb + j] = gb[j];
            }
        }
    }
}

// ---------------------------------------------------------------------------
// Aux kernel
// ---------------------------------------------------------------------------
__global__ __launch_bounds__(256) void aux_kernel(
    const float* __restrict__ colsum,
    float* __restrict__ auxAttn, float* __restrict__ auxKnow)
{
    __shared__ float s_a[4];
    __shared__ float s_b[4];
    const int tid = threadIdx.x;
    const int lane = tid & 63, wv = tid >> 6;
    const float invM = 1.f / 4096.f;

    float sa = 0.f;
    const float tqk = 1.f / 4096.f;
    for (int i = tid; i < 3 * N_QK; i += 256) {
        float m = colsum[i] * invM - tqk;
        sa += m * m;
    }
    float sk = 0.f;
    const float tkn = 1.f / 8192.f;
    for (int i = tid; i < N_KNOW; i += 256) {
        float m = colsum[3 * N_QK + i] * invM - tkn;
        sk += m * m;
    }
#pragma unroll
    for (int o = 32; o > 0; o >>= 1) {
        sa += __shfl_down(sa, o, 64);
        sk += __shfl_down(sk, o, 64);
    }
    if (lane == 0) { s_a[wv] = sa; s_b[wv] = sk; }
    __syncthreads();
    if (tid == 0) {
        auxAttn[0] = (s_a[0] + s_a[1] + s_a[2] + s_a[3]) * 4096.f;
        auxKnow[0] = (s_b[0] + s_b[1] + s_b[2] + s_b[3]) * 8192.f;
    }
}

// ---------------------------------------------------------------------------
// Launch
// ---------------------------------------------------------------------------
extern "C" void kernel_launch(void* const* d_in, const int* in_sizes, int n_in,
                              void* d_out, int out_size, void* d_ws, size_t ws_size,
                              hipStream_t stream)
{
    const float* x        = (const float*)d_in[0];
    const float* qk_emb   = (const float*)d_in[1];
    const float* v_emb    = (const float*)d_in[2];
    const float* know_emb = (const float*)d_in[3];
    const float* w_attn   = (const float*)d_in[4];
    const float* b_attn   = (const float*)d_in[5];
    const float* w_know   = (const float*)d_in[6];
    const float* b_know   = (const float*)d_in[7];
    float* out = (float*)d_out;

    const long long M = M_ROWS;
    const long long rowB = (long long)KX * 2;  // 8192 B per bf16x4 row

    float* gQ   = out;
    float* gK   = gQ + (size_t)M * N_QK;
    float* gV   = gK + (size_t)M * N_QK;
    float* auxA = gV + (size_t)M * N_QK;
    float* gKn  = auxA + 1;                    // NOTE: only 4-byte aligned
    float* auxK = gKn + (size_t)M * N_KNOW;

    // ---- ws plan (long long arithmetic; scores live in d_out) ----
    const long long nColsum = 3 * N_QK + N_KNOW;
    const long long tail_bytes = (M * 4 + nColsum) * 4;
    long long tailStart = ((long long)ws_size - tail_bytes) & ~255LL;
    float* tau4 = (float*)((char*)d_ws + tailStart);
    float* colsums = tau4 + (size_t)M * 4;

    long long ra, nb;
    if (M * rowB + 128 * rowB <= tailStart) {
        ra = M;
        nb = ((tailStart - M * rowB) / rowB / 128) * 128;
    } else {
        ra = ((tailStart / 2) / rowB / 128) * 128;
        if (ra < 128) ra = 128;
        if (ra > M) ra = M;
        nb = ((tailStart - ra * rowB) / rowB / 128) * 128;
        if (nb < 128) nb = 128;
    }
    ushortT* A_ext = (ushortT*)d_ws;
    ushortT* B_ext = (ushortT*)((char*)d_ws + ra * rowB);

    hipMemsetAsync(colsums, 0, nColsum * sizeof(float), stream);
    tau_kernel<<<(int)M, 256, 0, stream>>>(x, w_attn, b_attn, w_know, b_know, tau4, DIM);

    bool aConv = false;
    auto runStage = [&](const float* emb, int N, int ksel, int tA, int tB,
                        float* oA, float* oB, float* cA, float* cB) {
        long long NB = nb < N ? nb : N;
        for (long long n0 = 0; n0 < N; n0 += NB) {
            long long nc = (N - n0 < NB) ? (N - n0) : NB;
            {
                int nel4 = (int)(nc * 256);
                convert_ext<false><<<(nel4 + 255) / 256, 256, 0, stream>>>(
                    emb + n0 * DIM, B_ext, nel4);
            }
            for (long long a0 = 0; a0 < M; a0 += ra) {
                long long ac = (M - a0 < ra) ? (M - a0) : ra;
                if (ra < M || !aConv) {
                    int nel4 = (int)(ac * 256);
                    convert_ext<true><<<(nel4 + 255) / 256, 256, 0, stream>>>(
                        x + a0 * DIM, A_ext, nel4);
                    if (ra >= M) aConv = true;
                }
                gemm_bt_bf16x4<<<dim3((unsigned)(nc / 128), (unsigned)(ac / 128)), 256, 0, stream>>>(
                    A_ext, B_ext, oA + a0 * N + n0, N);
            }
        }
        if (N == N_QK)
            gate_kernel2<4, true><<<(int)M, 256, 0, stream>>>(
                oA, N, tau4, tA, tB, ksel, oA, oB, cA, cB);
        else
            gate_kernel2<8, false><<<(int)M, 256, 0, stream>>>(
                oA, N, tau4, tA, tB, ksel, oA, nullptr, cA, nullptr);
    };

    // qk scores -> gQ region (in-place gate writes gQ + gK; shared selection)
    runStage(qk_emb, N_QK, 64, 0, 1, gQ, gK, colsums, colsums + N_QK);
    // v scores -> gV
    runStage(v_emb, N_QK, 64, 2, -1, gV, nullptr, colsums + 2 * N_QK, nullptr);
    // know scores -> gKn (4-byte aligned region: scalar path)
    runStage(know_emb, N_KNOW, 128, 3, -1, gKn, nullptr, colsums + 3 * N_QK, nullptr);

    aux_kernel<<<1, 256, 0, stream>>>(colsums, auxA, auxK);
}

// Round 5
// 1184.134 us; speedup vs baseline: 2.0159x; 1.1427x over previous
//
#include <hip/hip_runtime.h>
#include <hip/hip_bf16.h>

// ---------------------------------------------------------------------------
// B=2,S=2048,D=1024; M=4096 rows. N_QK=N_V=4096, N_KNOW=8192.
// bf16x4 split GEMM (K-extended to 4096) on MFMA -> fp32-class scores written
// directly into d_out regions; gate kernels run IN-PLACE on those regions.
//   A' = [x_hi | x_hi | x_lo | x_lo]   (per 1024-dim row)
//   B' = [e_hi | e_lo | e_hi | e_lo]
// LDS staging uses seg XOR swizzle (seg' = seg ^ (row&7)) to break the
// 16-way bank conflict of the naive [128][64] layout (row stride = 32 banks).
// ---------------------------------------------------------------------------

#define M_ROWS 4096
#define DIM    1024
#define KX     4096   // 4*DIM
#define N_QK   4096
#define N_KNOW 8192

typedef unsigned short ushortT;
typedef __attribute__((ext_vector_type(8))) short short8;   // 8 bf16 (4 VGPR)
typedef __attribute__((ext_vector_type(4))) float f32x4;

// ---------------------------------------------------------------------------
// tau kernel
// ---------------------------------------------------------------------------
__global__ __launch_bounds__(256) void tau_kernel(
    const float* __restrict__ x, const float* __restrict__ w_attn,
    const float* __restrict__ b_attn, const float* __restrict__ w_know,
    const float* __restrict__ b_know, float* __restrict__ tau4, int D)
{
    __shared__ float s_f[4][4];
    const int row = blockIdx.x;
    const int tid = threadIdx.x;
    const float* xr = x + (size_t)row * D;
    float p0 = 0.f, p1 = 0.f, p2 = 0.f, p3 = 0.f;
    for (int d = tid; d < D; d += 256) {
        float xv = xr[d];
        p0 += xv * w_attn[d * 3 + 0];
        p1 += xv * w_attn[d * 3 + 1];
        p2 += xv * w_attn[d * 3 + 2];
        p3 += xv * w_know[d];
    }
#pragma unroll
    for (int o = 32; o > 0; o >>= 1) {
        p0 += __shfl_down(p0, o, 64);
        p1 += __shfl_down(p1, o, 64);
        p2 += __shfl_down(p2, o, 64);
        p3 += __shfl_down(p3, o, 64);
    }
    const int lane = tid & 63, wv = tid >> 6;
    if (lane == 0) { s_f[wv][0] = p0; s_f[wv][1] = p1; s_f[wv][2] = p2; s_f[wv][3] = p3; }
    __syncthreads();
    if (tid < 4) {
        float v = s_f[0][tid] + s_f[1][tid] + s_f[2][tid] + s_f[3][tid];
        v += (tid < 3) ? b_attn[tid] : b_know[0];
        tau4[(size_t)row * 4 + tid] = v;
    }
}

// ---------------------------------------------------------------------------
// convert: rows x 1024 fp32 -> rows x 4096 bf16.
//   MODE_A: [H | H | L | L]     MODE_B: [H | L | H | L]
// ---------------------------------------------------------------------------
template <bool IS_A>
__global__ __launch_bounds__(256) void convert_ext(
    const float* __restrict__ src, ushortT* __restrict__ dst, int nElem4)
{
    int g = blockIdx.x * 256 + threadIdx.x;
    if (g >= nElem4) return;
    int row = g >> 8;            // 256 float4 groups per row
    int k4  = (g & 255) << 2;    // 0..1020
    const float4 v = *(const float4*)(src + (size_t)row * DIM + k4);
    float vv[4] = {v.x, v.y, v.z, v.w};
    ushortT hi[4], lo[4];
#pragma unroll
    for (int i = 0; i < 4; i++) {
        __hip_bfloat16 hb = __float2bfloat16(vv[i]);
        float r = vv[i] - __bfloat162float(hb);
        __hip_bfloat16 lb = __float2bfloat16(r);
        hi[i] = *(ushortT*)&hb; lo[i] = *(ushortT*)&lb;
    }
    ushort4 H = make_ushort4(hi[0], hi[1], hi[2], hi[3]);
    ushort4 L = make_ushort4(lo[0], lo[1], lo[2], lo[3]);
    ushortT* drow = dst + (size_t)row * KX;
    if (IS_A) {
        *(ushort4*)(drow + k4)            = H;
        *(ushort4*)(drow + DIM + k4)      = H;
        *(ushort4*)(drow + 2 * DIM + k4)  = L;
        *(ushort4*)(drow + 3 * DIM + k4)  = L;
    } else {
        *(ushort4*)(drow + k4)            = H;
        *(ushort4*)(drow + DIM + k4)      = L;
        *(ushort4*)(drow + 2 * DIM + k4)  = H;
        *(ushort4*)(drow + 3 * DIM + k4)  = L;
    }
}

// ---------------------------------------------------------------------------
// bf16 NT GEMM: 128x128 tile, BK=64, 256 thr = 2x2 waves, 64x64/wave,
// 4x4 of 16x16x32 MFMA. LDS [128 rows][8 segs of 16B], seg XOR swizzle:
//   LDS slot (r, sp) holds global segment sp ^ (r & 7).
// Staging: global_load_lds width=16; lane's global seg permuted within the
// same 128B line (coalescing preserved); LDS dst contiguous (HW constraint).
// Fragment read: global seg s of row r at slot (r, s ^ (r&7)) -> lanes of a
// quad spread over 8 bank groups, 2-way (free) instead of 16-way.
// ---------------------------------------------------------------------------
__global__ __launch_bounds__(256) void gemm_bt_bf16x4(
    const ushortT* __restrict__ A, const ushortT* __restrict__ B,
    float* __restrict__ C, long long ldc)
{
    __shared__ ushortT As[128 * 64];
    __shared__ ushortT Bs[128 * 64];
    const int tid = threadIdx.x;
    const int wave = tid >> 6, lane = tid & 63;
    const int quad = lane >> 4, l16 = lane & 15;
    const int rx7 = l16 & 7;           // (row & 7) for all fragment rows
    const int wm = (wave >> 1) * 64, wn = (wave & 1) * 64;
    const long long m0 = (long long)blockIdx.y * 128;
    const long long n0 = (long long)blockIdx.x * 128;

    f32x4 acc[4][4] = {};

    const ushortT* gA[4];
    const ushortT* gB[4];
    ushortT* lA[4];
    ushortT* lB[4];
#pragma unroll
    for (int it = 0; it < 4; ++it) {
        int f = it * 256 + tid;          // 0..1023 flat 16B slot
        int r = f >> 3, sp = f & 7;      // row 0..127, lds seg 0..7
        int sg = sp ^ (r & 7);           // global segment stored in this slot
        gA[it] = A + (m0 + r) * KX + sg * 8;
        gB[it] = B + (n0 + r) * KX + sg * 8;
        lA[it] = As + f * 8;             // 16 B per slot (contiguous in lane)
        lB[it] = Bs + f * 8;
    }
    const ushortT* pAr[4];
    const ushortT* pBr[4];
#pragma unroll
    for (int t = 0; t < 4; ++t) {
        pAr[t] = As + (wm + t * 16 + l16) * 64;
        pBr[t] = Bs + (wn + t * 16 + l16) * 64;
    }

    for (int k0 = 0; k0 < KX; k0 += 64) {
#pragma unroll
        for (int it = 0; it < 4; ++it) {
            __builtin_amdgcn_global_load_lds(
                (const __attribute__((address_space(1))) unsigned*)(const void*)(gA[it] + k0),
                (__attribute__((address_space(3))) unsigned*)(void*)lA[it], 16, 0, 0);
            __builtin_amdgcn_global_load_lds(
                (const __attribute__((address_space(1))) unsigned*)(const void*)(gB[it] + k0),
                (__attribute__((address_space(3))) unsigned*)(void*)lB[it], 16, 0, 0);
        }
        __syncthreads();
#pragma unroll
        for (int ks = 0; ks < 2; ++ks) {
            const int so = (((ks * 4 + quad) ^ rx7)) * 8;  // swizzled seg offset
            short8 af[4], bfr[4];
#pragma unroll
            for (int t = 0; t < 4; ++t) {
                af[t]  = *(const short8*)(pAr[t] + so);
                bfr[t] = *(const short8*)(pBr[t] + so);
            }
#pragma unroll
            for (int i = 0; i < 4; ++i)
#pragma unroll
                for (int j = 0; j < 4; ++j)
                    acc[i][j] = __builtin_amdgcn_mfma_f32_16x16x32_bf16(af[i], bfr[j], acc[i][j], 0, 0, 0);
        }
        __syncthreads();
    }
    // C/D layout: col=lane&15, row=quad*4+reg  [m89/m91 verified]
#pragma unroll
    for (int i = 0; i < 4; ++i)
#pragma unroll
        for (int j = 0; j < 4; ++j) {
            long long col = n0 + wn + j * 16 + l16;
            long long rbase = m0 + wm + i * 16 + quad * 4;
#pragma unroll
            for (int r = 0; r < 4; ++r)
                C[(rbase + r) * ldc + col] = acc[i][j][r];
        }
}

// ---------------------------------------------------------------------------
// Gate kernel: one block/row, keys in registers, exact tie-correct top-k via
// bitwise binary search (early exit when count==k). Runs IN-PLACE on the
// score row (each thread only writes the indices it itself read).
// ---------------------------------------------------------------------------
__device__ __forceinline__ unsigned floatToKey(float f) {
    unsigned b = __float_as_uint(f);
    return (b & 0x80000000u) ? ~b : (b | 0x80000000u);
}
__device__ __forceinline__ float keyToFloat(unsigned key) {
    unsigned b = (key & 0x80000000u) ? (key & 0x7FFFFFFFu) : ~key;
    return __uint_as_float(b);
}
__device__ __forceinline__ float egate(float raw) {
    float g = raw > 0.f ? raw : 1e-8f * __expf(raw);
    return expf(g) - 1.f;
}

template <int NV, bool VEC4>
__global__ __launch_bounds__(256) void gate_kernel2(
    const float* __restrict__ scores, int N,
    const float* __restrict__ tau4, int tauA, int tauB,
    int ksel, float* __restrict__ outA, float* __restrict__ outB,
    float* __restrict__ colA, float* __restrict__ colB)
{
    __shared__ int s_i[4];
    __shared__ unsigned s_u[4];
    __shared__ float s_f[8];
    const int tid = threadIdx.x, lane = tid & 63, wv = tid >> 6;
    const int row = blockIdx.x;
    const bool hasB = (outB != nullptr);
    const float* srow = scores + (size_t)row * N;

    unsigned keys[NV * 4];
    unsigned kmax = 0u;
#pragma unroll
    for (int i = 0; i < NV; i++) {
        float v0, v1, v2, v3;
        const size_t nb = (size_t)(i * 256 + tid) * 4;
        if (VEC4) {
            float4 v = *(const float4*)(srow + nb);
            v0 = v.x; v1 = v.y; v2 = v.z; v3 = v.w;
        } else {
            v0 = srow[nb + 0]; v1 = srow[nb + 1];
            v2 = srow[nb + 2]; v3 = srow[nb + 3];
        }
        unsigned a = floatToKey(v0), b = floatToKey(v1);
        unsigned c = floatToKey(v2), d = floatToKey(v3);
        keys[i * 4 + 0] = a; keys[i * 4 + 1] = b;
        keys[i * 4 + 2] = c; keys[i * 4 + 3] = d;
        unsigned m1 = a > b ? a : b, m2 = c > d ? c : d;
        m1 = m1 > m2 ? m1 : m2;
        kmax = kmax > m1 ? kmax : m1;
    }
#pragma unroll
    for (int o = 32; o > 0; o >>= 1) {
        unsigned x = __shfl_down(kmax, o, 64);
        kmax = kmax > x ? kmax : x;
    }
    if (lane == 0) s_u[wv] = kmax;
    __syncthreads();
    { unsigned a = s_u[0], b = s_u[1], c = s_u[2], d = s_u[3];
      unsigned m1 = a > b ? a : b, m2 = c > d ? c : d; kmax = m1 > m2 ? m1 : m2; }
    __syncthreads();

    unsigned lo = 0u, hi = kmax, vk;
    for (;;) {
        if (lo >= hi) { vk = lo; break; }
        unsigned mid = lo + ((hi - lo + 1u) >> 1);
        int c = 0;
#pragma unroll
        for (int i = 0; i < NV * 4; i++) c += (keys[i] >= mid) ? 1 : 0;
#pragma unroll
        for (int o = 32; o > 0; o >>= 1) c += __shfl_down(c, o, 64);
        if (lane == 0) s_i[wv] = c;
        __syncthreads();
        int total = s_i[0] + s_i[1] + s_i[2] + s_i[3];
        __syncthreads();
        if (total == ksel) { vk = mid; break; }   // exact top-k set isolated
        if (total > ksel) lo = mid; else hi = mid - 1u;
    }

    const float tA = tau4[(size_t)row * 4 + tauA];
    const float tB = hasB ? tau4[(size_t)row * 4 + tauB] : 0.f;
    float sA = 0.f, sB = 0.f;
#pragma unroll
    for (int i = 0; i < NV * 4; i++) {
        if (keys[i] >= vk) {
            float s = keyToFloat(keys[i]);
            sA += egate(s - tA);
            if (hasB) sB += egate(s - tB);
        }
    }
#pragma unroll
    for (int o = 32; o > 0; o >>= 1) {
        sA += __shfl_down(sA, o, 64);
        sB += __shfl_down(sB, o, 64);
    }
    if (lane == 0) { s_f[wv] = sA; s_f[4 + wv] = sB; }
    __syncthreads();
    sA = s_f[0] + s_f[1] + s_f[2] + s_f[3];
    sB = s_f[4] + s_f[5] + s_f[6] + s_f[7];

    const float smax = keyToFloat(kmax);
    const float scaleA = tanhf(egate(smax - tA)) / (sA + 1e-8f);
    const float scaleB = hasB ? tanhf(egate(smax - tB)) / (sB + 1e-8f) : 0.f;

    float* orowA = outA + (size_t)row * N;
    float* orowB = hasB ? outB + (size_t)row * N : nullptr;
#pragma unroll
    for (int i = 0; i < NV; i++) {
        const size_t nb = (size_t)(i * 256 + tid) * 4;
        float ga[4], gb[4];
#pragma unroll
        for (int j = 0; j < 4; j++) {
            unsigned key = keys[i * 4 + j];
            float vA = 0.f, vB = 0.f;
            if (key >= vk) {
                float s = keyToFloat(key);
                vA = egate(s - tA) * scaleA;
                atomicAdd(&colA[nb + j], vA);
                if (hasB) { vB = egate(s - tB) * scaleB; atomicAdd(&colB[nb + j], vB); }
            }
            ga[j] = vA; gb[j] = vB;
        }
        if (VEC4) {
            *(float4*)(orowA + nb) = make_float4(ga[0], ga[1], ga[2], ga[3]);
            if (hasB) *(float4*)(orowB + nb) = make_float4(gb[0], gb[1], gb[2], gb[3]);
        } else {
#pragma unroll
            for (int j = 0; j < 4; j++) {
                orowA[nb + j] = ga[j];
                if (hasB) orowB[nb + j] = gb[j];
            }
        }
    }
}

// ---------------------------------------------------------------------------
// Aux kernel
// ---------------------------------------------------------------------------
__global__ __launch_bounds__(256) void aux_kernel(
    const float* __restrict__ colsum,
    float* __restrict__ auxAttn, float* __restrict__ auxKnow)
{
    __shared__ float s_a[4];
    __shared__ float s_b[4];
    const int tid = threadIdx.x;
    const int lane = tid & 63, wv = tid >> 6;
    const float invM = 1.f / 4096.f;

    float sa = 0.f;
    const float tqk = 1.f / 4096.f;
    for (int i = tid; i < 3 * N_QK; i += 256) {
        float m = colsum[i] * invM - tqk;
        sa += m * m;
    }
    float sk = 0.f;
    const float tkn = 1.f / 8192.f;
    for (int i = tid; i < N_KNOW; i += 256) {
        float m = colsum[3 * N_QK + i] * invM - tkn;
        sk += m * m;
    }
#pragma unroll
    for (int o = 32; o > 0; o >>= 1) {
        sa += __shfl_down(sa, o, 64);
        sk += __shfl_down(sk, o, 64);
    }
    if (lane == 0) { s_a[wv] = sa; s_b[wv] = sk; }
    __syncthreads();
    if (tid == 0) {
        auxAttn[0] = (s_a[0] + s_a[1] + s_a[2] + s_a[3]) * 4096.f;
        auxKnow[0] = (s_b[0] + s_b[1] + s_b[2] + s_b[3]) * 8192.f;
    }
}

// ---------------------------------------------------------------------------
// Launch
// ---------------------------------------------------------------------------
extern "C" void kernel_launch(void* const* d_in, const int* in_sizes, int n_in,
                              void* d_out, int out_size, void* d_ws, size_t ws_size,
                              hipStream_t stream)
{
    const float* x        = (const float*)d_in[0];
    const float* qk_emb   = (const float*)d_in[1];
    const float* v_emb    = (const float*)d_in[2];
    const float* know_emb = (const float*)d_in[3];
    const float* w_attn   = (const float*)d_in[4];
    const float* b_attn   = (const float*)d_in[5];
    const float* w_know   = (const float*)d_in[6];
    const float* b_know   = (const float*)d_in[7];
    float* out = (float*)d_out;

    const long long M = M_ROWS;
    const long long rowB = (long long)KX * 2;  // 8192 B per bf16x4 row

    float* gQ   = out;
    float* gK   = gQ + (size_t)M * N_QK;
    float* gV   = gK + (size_t)M * N_QK;
    float* auxA = gV + (size_t)M * N_QK;
    float* gKn  = auxA + 1;                    // NOTE: only 4-byte aligned
    float* auxK = gKn + (size_t)M * N_KNOW;

    // ---- ws plan (long long arithmetic; scores live in d_out) ----
    const long long nColsum = 3 * N_QK + N_KNOW;
    const long long tail_bytes = (M * 4 + nColsum) * 4;
    long long tailStart = ((long long)ws_size - tail_bytes) & ~255LL;
    float* tau4 = (float*)((char*)d_ws + tailStart);
    float* colsums = tau4 + (size_t)M * 4;

    long long ra, nb;
    if (M * rowB + 128 * rowB <= tailStart) {
        ra = M;
        nb = ((tailStart - M * rowB) / rowB / 128) * 128;
    } else {
        ra = ((tailStart / 2) / rowB / 128) * 128;
        if (ra < 128) ra = 128;
        if (ra > M) ra = M;
        nb = ((tailStart - ra * rowB) / rowB / 128) * 128;
        if (nb < 128) nb = 128;
    }
    ushortT* A_ext = (ushortT*)d_ws;
    ushortT* B_ext = (ushortT*)((char*)d_ws + ra * rowB);

    hipMemsetAsync(colsums, 0, nColsum * sizeof(float), stream);
    tau_kernel<<<(int)M, 256, 0, stream>>>(x, w_attn, b_attn, w_know, b_know, tau4, DIM);

    bool aConv = false;
    auto runStage = [&](const float* emb, int N, int ksel, int tA, int tB,
                        float* oA, float* oB, float* cA, float* cB) {
        long long NB = nb < N ? nb : N;
        for (long long n0 = 0; n0 < N; n0 += NB) {
            long long nc = (N - n0 < NB) ? (N - n0) : NB;
            {
                int nel4 = (int)(nc * 256);
                convert_ext<false><<<(nel4 + 255) / 256, 256, 0, stream>>>(
                    emb + n0 * DIM, B_ext, nel4);
            }
            for (long long a0 = 0; a0 < M; a0 += ra) {
                long long ac = (M - a0 < ra) ? (M - a0) : ra;
                if (ra < M || !aConv) {
                    int nel4 = (int)(ac * 256);
                    convert_ext<true><<<(nel4 + 255) / 256, 256, 0, stream>>>(
                        x + a0 * DIM, A_ext, nel4);
                    if (ra >= M) aConv = true;
                }
                gemm_bt_bf16x4<<<dim3((unsigned)(nc / 128), (unsigned)(ac / 128)), 256, 0, stream>>>(
                    A_ext, B_ext, oA + a0 * N + n0, N);
            }
        }
        if (N == N_QK)
            gate_kernel2<4, true><<<(int)M, 256, 0, stream>>>(
                oA, N, tau4, tA, tB, ksel, oA, oB, cA, cB);
        else
            gate_kernel2<8, false><<<(int)M, 256, 0, stream>>>(
                oA, N, tau4, tA, tB, ksel, oA, nullptr, cA, nullptr);
    };

    // qk scores -> gQ region (in-place gate writes gQ + gK; shared selection)
    runStage(qk_emb, N_QK, 64, 0, 1, gQ, gK, colsums, colsums + N_QK);
    // v scores -> gV
    runStage(v_emb, N_QK, 64, 2, -1, gV, nullptr, colsums + 2 * N_QK, nullptr);
    // know scores -> gKn (4-byte aligned region: scalar path)
    runStage(know_emb, N_KNOW, 128, 3, -1, gKn, nullptr, colsums + 3 * N_QK, nullptr);

    aux_kernel<<<1, 256, 0, stream>>>(colsums, auxA, auxK);
}